// Round 1
// baseline (333.312 us; speedup 1.0000x reference)
//
#include <hip/hip_runtime.h>
#include <math.h>

#define BATCH 32
#define CH    768
#define HW    3136        // 56*56
#define K2C   1536        // 2*CH
#define BN_EPS 1e-5f

// ---------------- K1: per-(b,c) avg + max pool over HW ----------------
__global__ __launch_bounds__(256) void pool_kernel(const float* __restrict__ x,
                                                   float* __restrict__ avg,
                                                   float* __restrict__ mx) {
    const int bc = blockIdx.x;                       // 0 .. B*C-1
    const float4* row = (const float4*)(x + (size_t)bc * HW);
    const int t = threadIdx.x;
    float s = 0.f, m = -INFINITY;
    for (int q = t; q < HW / 4; q += 256) {          // 784 float4 per row
        float4 v = row[q];
        s += v.x + v.y + v.z + v.w;
        m = fmaxf(m, fmaxf(fmaxf(v.x, v.y), fmaxf(v.z, v.w)));
    }
    // wave (64-lane) reduction
    for (int off = 32; off > 0; off >>= 1) {
        s += __shfl_down(s, off);
        m = fmaxf(m, __shfl_down(m, off));
    }
    __shared__ float ss[4], sm[4];
    const int wave = t >> 6, lane = t & 63;
    if (lane == 0) { ss[wave] = s; sm[wave] = m; }
    __syncthreads();
    if (t == 0) {
        float fs = ss[0] + ss[1] + ss[2] + ss[3];
        float fm = fmaxf(fmaxf(sm[0], sm[1]), fmaxf(sm[2], sm[3]));
        avg[bc] = fs * (1.0f / (float)HW);
        mx[bc]  = fm;
    }
}

// ---------------- K2: im = concat(avg,max) @ W^T + b, then BN ----------------
__global__ __launch_bounds__(256) void mlp_bn_kernel(const float* __restrict__ avg,
                                                     const float* __restrict__ mx,
                                                     const float* __restrict__ w,
                                                     const float* __restrict__ bias,
                                                     const float* __restrict__ gamma,
                                                     const float* __restrict__ beta,
                                                     const float* __restrict__ mean,
                                                     const float* __restrict__ var,
                                                     float* __restrict__ im) {
    const int idx = blockIdx.x * 256 + threadIdx.x;  // 0 .. B*C-1
    const int b = idx / CH, co = idx % CH;
    const float4* w4 = (const float4*)(w + (size_t)co * K2C);
    const float4* a4 = (const float4*)(avg + b * CH);
    const float4* m4 = (const float4*)(mx + b * CH);
    float acc = 0.f;
    #pragma unroll 4
    for (int j = 0; j < CH / 4; ++j) {               // avg half: k = 0..767
        float4 wv = w4[j], av = a4[j];
        acc += wv.x * av.x + wv.y * av.y + wv.z * av.z + wv.w * av.w;
    }
    #pragma unroll 4
    for (int j = 0; j < CH / 4; ++j) {               // max half: k = 768..1535
        float4 wv = w4[CH / 4 + j], mv = m4[j];
        acc += wv.x * mv.x + wv.y * mv.y + wv.z * mv.z + wv.w * mv.w;
    }
    float y = acc + bias[co];
    y = (y - mean[co]) * (gamma[co] * rsqrtf(var[co] + BN_EPS)) + beta[co];
    im[idx] = y;
}

// ---------------- K3: att[b,p] = sum_c im[b,c] * x[b,c,p] ----------------
// block = 256 thr = 4 c-groups x 64 lanes; each lane owns a float4 of positions
__global__ __launch_bounds__(256) void att_kernel(const float* __restrict__ x,
                                                  const float* __restrict__ im,
                                                  float* __restrict__ att) {
    const int b  = blockIdx.y;
    const int p0 = blockIdx.x * 256;                 // 256 positions per block
    const int t  = threadIdx.x;
    const int lane = t & 63, cg = t >> 6;

    __shared__ float im_s[CH];
    for (int i = t; i < CH; i += 256) im_s[i] = im[b * CH + i];
    __syncthreads();

    const int p = p0 + 4 * lane;
    float4 acc = {0.f, 0.f, 0.f, 0.f};
    if (p < HW) {
        const float* xb = x + (size_t)b * CH * HW;
        for (int c = cg; c < CH; c += 4) {
            float4 v = *(const float4*)(xb + (size_t)c * HW + p);
            const float wgt = im_s[c];
            acc.x += wgt * v.x; acc.y += wgt * v.y;
            acc.z += wgt * v.z; acc.w += wgt * v.w;
        }
    }
    __shared__ float4 part[4][64];
    part[cg][lane] = acc;
    __syncthreads();
    if (t < 64 && p < HW) {
        float4 r0 = part[0][lane], r1 = part[1][lane],
               r2 = part[2][lane], r3 = part[3][lane];
        float4 r;
        r.x = r0.x + r1.x + r2.x + r3.x;
        r.y = r0.y + r1.y + r2.y + r3.y;
        r.z = r0.z + r1.z + r2.z + r3.z;
        r.w = r0.w + r1.w + r2.w + r3.w;
        *(float4*)(att + (size_t)b * HW + p) = r;
    }
}

// ---------------- K4: out[b,c,p] = att[b,p] * x[b,c,p] ----------------
__global__ __launch_bounds__(256) void gate_kernel(const float* __restrict__ x,
                                                   const float* __restrict__ att,
                                                   float* __restrict__ out) {
    const int bc = blockIdx.x;                       // 0 .. B*C-1
    const int b = bc / CH;
    const float4* xr = (const float4*)(x + (size_t)bc * HW);
    const float4* ar = (const float4*)(att + (size_t)b * HW);
    float4* orow = (float4*)(out + (size_t)bc * HW);
    for (int q = threadIdx.x; q < HW / 4; q += 256) {
        float4 v = xr[q], a = ar[q];
        float4 r = {a.x * v.x, a.y * v.y, a.z * v.z, a.w * v.w};
        orow[q] = r;
    }
}

extern "C" void kernel_launch(void* const* d_in, const int* in_sizes, int n_in,
                              void* d_out, int out_size, void* d_ws, size_t ws_size,
                              hipStream_t stream) {
    const float* x      = (const float*)d_in[0];
    const float* conv_w = (const float*)d_in[1];
    const float* conv_b = (const float*)d_in[2];
    const float* gamma  = (const float*)d_in[3];
    const float* beta   = (const float*)d_in[4];
    const float* mean   = (const float*)d_in[5];
    const float* var    = (const float*)d_in[6];
    float* out = (float*)d_out;

    float* ws  = (float*)d_ws;
    float* avg = ws;                    // B*C = 24576
    float* mx  = ws + 24576;            // B*C
    float* im  = ws + 49152;            // B*C
    float* att = ws + 73728;            // B*HW = 100352

    pool_kernel<<<BATCH * CH, 256, 0, stream>>>(x, avg, mx);
    mlp_bn_kernel<<<(BATCH * CH) / 256, 256, 0, stream>>>(avg, mx, conv_w, conv_b,
                                                          gamma, beta, mean, var, im);
    att_kernel<<<dim3((HW + 255) / 256, BATCH), 256, 0, stream>>>(x, im, att);
    gate_kernel<<<BATCH * CH, 256, 0, stream>>>(x, att, out);
}

// Round 2
// 235.483 us; speedup vs baseline: 1.4154x; 1.4154x over previous
//
#include <hip/hip_runtime.h>
#include <math.h>

#define BATCH 32
#define CH    768
#define HW    3136        // 56*56
#define K2C   1536        // 2*CH
#define BN_EPS 1e-5f

typedef float fv4 __attribute__((ext_vector_type(4)));

// ---------------- K1: per-(b,c) avg + max pool, one wave per row ----------------
__global__ __launch_bounds__(256) void pool_kernel(const float* __restrict__ x,
                                                   float* __restrict__ avg,
                                                   float* __restrict__ mx) {
    const int wave = threadIdx.x >> 6, lane = threadIdx.x & 63;
    const int bc = blockIdx.x * 4 + wave;            // 0 .. B*C-1
    const fv4* row = (const fv4*)(x + (size_t)bc * HW);
    float s = 0.f, m = -INFINITY;
    for (int q = lane; q < HW / 4; q += 64) {        // 784 fv4 per row
        fv4 v = row[q];
        s += v.x + v.y + v.z + v.w;
        m = fmaxf(m, fmaxf(fmaxf(v.x, v.y), fmaxf(v.z, v.w)));
    }
    for (int off = 32; off; off >>= 1) {
        s += __shfl_down(s, off);
        m = fmaxf(m, __shfl_down(m, off));
    }
    if (lane == 0) {
        avg[bc] = s * (1.0f / (float)HW);
        mx[bc]  = m;
    }
}

// ---------------- K2: im = concat(avg,max) @ W^T + b, then BN ----------------
// grid = (B/2) x (CH/16); block 256 = 16 co x 16 k-parts; 2 batches/thread
__global__ __launch_bounds__(256) void mlp_bn_kernel(const float* __restrict__ avg,
                                                     const float* __restrict__ mx,
                                                     const float* __restrict__ w,
                                                     const float* __restrict__ bias,
                                                     const float* __restrict__ gamma,
                                                     const float* __restrict__ beta,
                                                     const float* __restrict__ mean,
                                                     const float* __restrict__ var,
                                                     float* __restrict__ im) {
    const int b0 = blockIdx.x * 2, b1 = b0 + 1;
    const int t  = threadIdx.x;
    const int co = blockIdx.y * 16 + (t >> 4);       // output channel
    const int kp = t & 15;                           // k-part: 96 floats each
    // k range [kp*96, kp*96+96): entirely in avg half (kp<8) or max half (kp>=8)
    const float* s0;
    const float* s1;
    if (kp < 8) {
        s0 = avg + b0 * CH + kp * 96;
        s1 = avg + b1 * CH + kp * 96;
    } else {
        s0 = mx + b0 * CH + (kp - 8) * 96;
        s1 = mx + b1 * CH + (kp - 8) * 96;
    }
    const fv4* wrow = (const fv4*)(w + (size_t)co * K2C + kp * 96);
    const fv4* v04  = (const fv4*)s0;
    const fv4* v14  = (const fv4*)s1;
    float a0 = 0.f, a1 = 0.f;
    #pragma unroll
    for (int j = 0; j < 24; ++j) {
        fv4 wv = wrow[j], u0 = v04[j], u1 = v14[j];
        a0 += wv.x * u0.x + wv.y * u0.y + wv.z * u0.z + wv.w * u0.w;
        a1 += wv.x * u1.x + wv.y * u1.y + wv.z * u1.z + wv.w * u1.w;
    }
    // reduce across 16 k-parts (lanes kp..kp+15 within the wave)
    for (int off = 8; off; off >>= 1) {
        a0 += __shfl_down(a0, off);
        a1 += __shfl_down(a1, off);
    }
    if (kp == 0) {
        const float scale = gamma[co] * rsqrtf(var[co] + BN_EPS);
        const float base  = beta[co] - mean[co] * scale;
        im[b0 * CH + co] = (a0 + bias[co]) * scale + base;
        im[b1 * CH + co] = (a1 + bias[co]) * scale + base;
    }
}

// ---------------- K3: fused att + gate ----------------
// block owns (b, 64 positions). Phase 1: att[p] = sum_c im[c]*x[b,c,p].
// Phase 2: out[b,c,p] = att[p]*x[b,c,p] (same addresses -> cache-hot reread).
__global__ __launch_bounds__(256) void att_gate_kernel(const float* __restrict__ x,
                                                       const float* __restrict__ im,
                                                       float* __restrict__ out) {
    const int b  = blockIdx.y;
    const int p0 = blockIdx.x * 64;                  // 64 positions = 16 fv4
    const int t  = threadIdx.x;
    const int cg = t >> 4, pidx = t & 15;            // 16 c-groups x 16 quads

    __shared__ float im_s[CH];
    for (int i = t; i < CH; i += 256) im_s[i] = im[b * CH + i];
    __syncthreads();

    const float* xb = x + (size_t)b * CH * HW + p0 + pidx * 4;
    fv4 acc = {0.f, 0.f, 0.f, 0.f};
    for (int c = cg; c < CH; c += 16) {
        fv4 v = *(const fv4*)(xb + (size_t)c * HW);
        acc += im_s[c] * v;
    }
    __shared__ fv4 part[16][16];
    part[cg][pidx] = acc;
    __syncthreads();
    __shared__ fv4 att_s[16];
    if (t < 16) {
        fv4 a = part[0][t];
        #pragma unroll
        for (int g = 1; g < 16; ++g) a += part[g][t];
        att_s[t] = a;
    }
    __syncthreads();
    const fv4 a4 = att_s[pidx];
    float* ob = out + (size_t)b * CH * HW + p0 + pidx * 4;
    for (int c = cg; c < CH; c += 16) {
        fv4 v = *(const fv4*)(xb + (size_t)c * HW);
        __builtin_nontemporal_store(v * a4, (fv4*)(ob + (size_t)c * HW));
    }
}

extern "C" void kernel_launch(void* const* d_in, const int* in_sizes, int n_in,
                              void* d_out, int out_size, void* d_ws, size_t ws_size,
                              hipStream_t stream) {
    const float* x      = (const float*)d_in[0];
    const float* conv_w = (const float*)d_in[1];
    const float* conv_b = (const float*)d_in[2];
    const float* gamma  = (const float*)d_in[3];
    const float* beta   = (const float*)d_in[4];
    const float* mean   = (const float*)d_in[5];
    const float* var    = (const float*)d_in[6];
    float* out = (float*)d_out;

    float* ws  = (float*)d_ws;
    float* avg = ws;                    // B*C = 24576
    float* mx  = ws + 24576;            // B*C
    float* im  = ws + 49152;            // B*C

    pool_kernel<<<(BATCH * CH) / 4, 256, 0, stream>>>(x, avg, mx);
    mlp_bn_kernel<<<dim3(BATCH / 2, CH / 16), 256, 0, stream>>>(avg, mx, conv_w, conv_b,
                                                                gamma, beta, mean, var, im);
    att_gate_kernel<<<dim3(HW / 64, BATCH), 256, 0, stream>>>(x, im, out);
}

// Round 3
// 220.385 us; speedup vs baseline: 1.5124x; 1.0685x over previous
//
#include <hip/hip_runtime.h>
#include <math.h>

#define BATCH 32
#define CH    768
#define HW    3136        // 56*56
#define K2C   1536        // 2*CH
#define BN_EPS 1e-5f

typedef float fv4 __attribute__((ext_vector_type(4)));

// ---------------- K1: per-(b,c) avg + max pool, one wave per row ----------------
__global__ __launch_bounds__(256) void pool_kernel(const float* __restrict__ x,
                                                   float* __restrict__ avg,
                                                   float* __restrict__ mx) {
    const int wave = threadIdx.x >> 6, lane = threadIdx.x & 63;
    const int bc = blockIdx.x * 4 + wave;            // 0 .. B*C-1
    const fv4* row = (const fv4*)(x + (size_t)bc * HW);
    float s = 0.f, m = -INFINITY;
    for (int q = lane; q < HW / 4; q += 64) {        // 784 fv4 per row
        fv4 v = row[q];
        s += v.x + v.y + v.z + v.w;
        m = fmaxf(m, fmaxf(fmaxf(v.x, v.y), fmaxf(v.z, v.w)));
    }
    for (int off = 32; off; off >>= 1) {
        s += __shfl_down(s, off);
        m = fmaxf(m, __shfl_down(m, off));
    }
    if (lane == 0) {
        avg[bc] = s * (1.0f / (float)HW);
        mx[bc]  = m;
    }
}

// ---------------- K2: im = concat(avg,max) @ W^T + b, then BN ----------------
// grid = (B/2) x (CH/16); block 256 = 16 co x 16 k-parts; 2 batches/thread
__global__ __launch_bounds__(256) void mlp_bn_kernel(const float* __restrict__ avg,
                                                     const float* __restrict__ mx,
                                                     const float* __restrict__ w,
                                                     const float* __restrict__ bias,
                                                     const float* __restrict__ gamma,
                                                     const float* __restrict__ beta,
                                                     const float* __restrict__ mean,
                                                     const float* __restrict__ var,
                                                     float* __restrict__ im) {
    const int b0 = blockIdx.x * 2, b1 = b0 + 1;
    const int t  = threadIdx.x;
    const int co = blockIdx.y * 16 + (t >> 4);       // output channel
    const int kp = t & 15;                           // k-part: 96 floats each
    const float* s0;
    const float* s1;
    if (kp < 8) {
        s0 = avg + b0 * CH + kp * 96;
        s1 = avg + b1 * CH + kp * 96;
    } else {
        s0 = mx + b0 * CH + (kp - 8) * 96;
        s1 = mx + b1 * CH + (kp - 8) * 96;
    }
    const fv4* wrow = (const fv4*)(w + (size_t)co * K2C + kp * 96);
    const fv4* v04  = (const fv4*)s0;
    const fv4* v14  = (const fv4*)s1;
    float a0 = 0.f, a1 = 0.f;
    #pragma unroll
    for (int j = 0; j < 24; ++j) {
        fv4 wv = wrow[j], u0 = v04[j], u1 = v14[j];
        a0 += wv.x * u0.x + wv.y * u0.y + wv.z * u0.z + wv.w * u0.w;
        a1 += wv.x * u1.x + wv.y * u1.y + wv.z * u1.z + wv.w * u1.w;
    }
    for (int off = 8; off; off >>= 1) {
        a0 += __shfl_down(a0, off);
        a1 += __shfl_down(a1, off);
    }
    if (kp == 0) {
        const float scale = gamma[co] * rsqrtf(var[co] + BN_EPS);
        const float base  = beta[co] - mean[co] * scale;
        im[b0 * CH + co] = (a0 + bias[co]) * scale + base;
        im[b1 * CH + co] = (a1 + bias[co]) * scale + base;
    }
}

// ---------------- K3: fused att + gate, x tile held in REGISTERS ----------------
// block = (b, 16 positions). thread t: cg = t>>2 (channel group, 0..63),
// pidx = t&3 (position quad). Holds x[cg + 64j][pidx quad] for j=0..11 in regs.
// Phase 1: att partial; shuffle+LDS reduce. Phase 2: gate from regs, NT store.
__global__ __launch_bounds__(256) void att_gate_kernel(const float* __restrict__ x,
                                                       const float* __restrict__ im,
                                                       float* __restrict__ out) {
    const int b    = blockIdx.y;
    const int p0   = blockIdx.x * 16;                // 16 positions = 4 quads
    const int t    = threadIdx.x;
    const int cg   = t >> 2;                         // 0..63
    const int pidx = t & 3;

    __shared__ float im_s[CH];
    {
        const fv4* src = (const fv4*)(im + b * CH);
        fv4* dst = (fv4*)im_s;
        for (int i = t; i < CH / 4; i += 256) dst[i] = src[i];
    }

    const float* xb = x + (size_t)b * CH * HW + p0 + pidx * 4;

    fv4 v[12];
    #pragma unroll
    for (int j = 0; j < 12; ++j)
        v[j] = *(const fv4*)(xb + (size_t)(cg + 64 * j) * HW);

    __syncthreads();                                 // im_s ready

    fv4 acc = {0.f, 0.f, 0.f, 0.f};
    #pragma unroll
    for (int j = 0; j < 12; ++j)
        acc += im_s[cg + 64 * j] * v[j];

    // intra-wave reduce: lanes 4 apart share pidx
    #pragma unroll
    for (int off = 4; off <= 32; off <<= 1) {
        acc.x += __shfl_down(acc.x, off);
        acc.y += __shfl_down(acc.y, off);
        acc.z += __shfl_down(acc.z, off);
        acc.w += __shfl_down(acc.w, off);
    }
    __shared__ fv4 part[4][4];                       // [wave][pidx]
    __shared__ fv4 att_s[4];
    const int wave = t >> 6, lane = t & 63;
    if (lane < 4) part[wave][lane] = acc;
    __syncthreads();
    if (t < 4) att_s[t] = part[0][t] + part[1][t] + part[2][t] + part[3][t];
    __syncthreads();

    const fv4 a4 = att_s[pidx];
    float* ob = out + (size_t)b * CH * HW + p0 + pidx * 4;
    #pragma unroll
    for (int j = 0; j < 12; ++j)
        __builtin_nontemporal_store(v[j] * a4,
                                    (fv4*)(ob + (size_t)(cg + 64 * j) * HW));
}

extern "C" void kernel_launch(void* const* d_in, const int* in_sizes, int n_in,
                              void* d_out, int out_size, void* d_ws, size_t ws_size,
                              hipStream_t stream) {
    const float* x      = (const float*)d_in[0];
    const float* conv_w = (const float*)d_in[1];
    const float* conv_b = (const float*)d_in[2];
    const float* gamma  = (const float*)d_in[3];
    const float* beta   = (const float*)d_in[4];
    const float* mean   = (const float*)d_in[5];
    const float* var    = (const float*)d_in[6];
    float* out = (float*)d_out;

    float* ws  = (float*)d_ws;
    float* avg = ws;                    // B*C = 24576
    float* mx  = ws + 24576;            // B*C
    float* im  = ws + 49152;            // B*C

    pool_kernel<<<(BATCH * CH) / 4, 256, 0, stream>>>(x, avg, mx);
    mlp_bn_kernel<<<dim3(BATCH / 2, CH / 16), 256, 0, stream>>>(avg, mx, conv_w, conv_b,
                                                                gamma, beta, mean, var, im);
    att_gate_kernel<<<dim3(HW / 16, BATCH), 256, 0, stream>>>(x, im, out);
}